// Round 2
// baseline (6913.480 us; speedup 1.0000x reference)
//
#include <hip/hip_runtime.h>
#include <cfloat>
#include <climits>

#define NPTS   8192
#define SCENT  2048
#define KNEIGH 32
#define BATCH  4
#define DFEAT  64
#define FPS_T  512
#define NV     8       // v2f pairs per thread PER BATCH (16 points)
#define NW     8       // waves per block
#define CAP    64      // fallback candidate capacity
#define PBLK   2       // producer blocks (2 batches each)
#define NCONS  252     // consumer blocks
#define CPB    63      // consumer blocks per batch

typedef float v2f __attribute__((ext_vector_type(2)));

// DPP top-2 (max + second-max) step over uints (positive-f32 bit pattern
// preserves order). Shifted-in lanes contribute 0 (harmless for max/sec).
#define DPPTOP2(um, us, ctrl, rmask)                                                  \
    { unsigned _tm = (unsigned)__builtin_amdgcn_update_dpp(0, (int)(um), (ctrl),      \
                                                           (rmask), 0xf, false);     \
      unsigned _ts = (unsigned)__builtin_amdgcn_update_dpp(0, (int)(us), (ctrl),      \
                                                           (rmask), 0xf, false);     \
      unsigned _lo = ((um) < _tm) ? (um) : _tm;                                       \
      (us) = ((us) > _ts) ? (us) : _ts;                                               \
      (us) = ((us) > _lo) ? (us) : _lo;                                               \
      (um) = ((um) > _tm) ? (um) : _tm; }

// Uniform 3-float load from global (index is block-uniform; readfirstlane
// lets the compiler use scalar loads; broadcast either way).
#define ULOAD3(Xp, idx, ox, oy, oz)                                                   \
    { const int _u = __builtin_amdgcn_readfirstlane(idx);                             \
      const float* _p = (Xp) + 3 * (size_t)_u;                                        \
      ox = _p[0]; oy = _p[1]; oz = _p[2]; }

// Barrier-free chunk flush + release publish, executed by wave qq only.
// All 192 stores belong to that wave => wave-local vmcnt(0) drains them.
// Newest 1-2 centroids come from registers; older entries were written to
// LDS history in earlier rounds (>=1 __syncthreads ago => visible).
#define FLUSH_Q(qq, gb, Eidx, VX, VY, VZ, HASPREV, PX, PY, PZ)                        \
    if (((Eidx) & 63) == 63) {                                                        \
        if (w == (qq)) {                                                              \
            const int base0 = (Eidx) - 63;                                            \
            for (int rep = 0; rep < 3; ++rep) {                                       \
                const int li = rep * 64 + lane;                                       \
                const int ci = base0 + li / 3;                                        \
                const int cc = li - (li / 3) * 3;                                     \
                float v;                                                              \
                if (ci == (Eidx))                                                     \
                    v = (cc == 0) ? (VX) : ((cc == 1) ? (VY) : (VZ));                 \
                else if ((HASPREV) && ci == (Eidx) - 1)                               \
                    v = (cc == 0) ? (PX) : ((cc == 1) ? (PY) : (PZ));                 \
                else                                                                  \
                    v = (cc == 0) ? S.hx[qq][ci]                                      \
                                  : ((cc == 1) ? S.hy[qq][ci] : S.hz[qq][ci]);        \
                __hip_atomic_store(&new_xyz[((size_t)(gb) * SCENT + base0) * 3 + li], \
                                   v, __ATOMIC_RELAXED, __HIP_MEMORY_SCOPE_AGENT);    \
            }                                                                         \
            asm volatile("s_waitcnt vmcnt(0)" ::: "memory");                          \
            if (lane == 0)                                                            \
                __hip_atomic_store(&progress[gb], (Eidx) + 1,                         \
                                   __ATOMIC_RELEASE, __HIP_MEMORY_SCOPE_AGENT);       \
        }                                                                             \
    }

struct FpsSh {                       // ~51 KB: 2 batches of history + slots
    float hx[2][SCENT], hy[2][SCENT], hz[2][SCENT];
    alignas(16) unsigned slotQ[2][2][NW][4];   // [batch][buf][wave]{m,metaM,sec,0}
    float scandX[CAP], scandY[CAP], scandZ[CAP];
    int   scandI[CAP];
    int   scnt;
    alignas(8) double sdd[2][NW];
    double sfv[NW];
    int sfo[NW];
};
struct ConsSh {                      // ~111 KB: KNN buffers + MLP weights
    float  spx[2048], spy[2048], spz[2048];
    double sp2[2048];
    float  tile[32 * 33];
    float  regA[64 * 68];            // w0 permuted/padded
    float  regB[64 * 64];            // w1
    float  regC[128 * 64];           // w2
    float  prm[512];
};
union ShU { FpsSh f; ConsSh c; };

// ---------------------------------------------------------------------------
// Fully fused cooperative kernel.
// Blocks 0..1: FPS producers, TWO batches per block interleaved on the same
// 512 threads (16 pts/thread/batch in registers). Per round: phase1 =
// update+DPP-top2+slot-write for A then B; ONE barrier; phase2 = combine +
// top-2 peel + emit for A then B. Batch A's serial tail (LDS slot reads,
// dependent uniform coord loads) hides under batch B's issue and vice versa.
// Flush/publish is barrier-free (single wave + wave-local vmcnt drain), so
// per-batch E divergence (from peeling) cannot deadlock. The rare f64-exact
// fallback is block-uniform (redundant combine on all threads) so its
// internal barriers stay safe.
// Blocks 2..253: consumers (transpose -> gated KNN -> per-wave MLP),
// unchanged from the proven R1 version.
// ---------------------------------------------------------------------------
__global__ __launch_bounds__(FPS_T, 1) void fused_kernel(
        const float* __restrict__ xyz, float* __restrict__ new_xyz,
        const float* __restrict__ pts, float* __restrict__ ptsT,
        int* __restrict__ progress, int* __restrict__ tcount,
        float* __restrict__ out_points,
        const float* __restrict__ w0, const float* __restrict__ g0,
        const float* __restrict__ b0, const float* __restrict__ m0,
        const float* __restrict__ v0, const float* __restrict__ w1,
        const float* __restrict__ g1, const float* __restrict__ b1,
        const float* __restrict__ m1, const float* __restrict__ v1,
        const float* __restrict__ w2, const float* __restrict__ g2,
        const float* __restrict__ b2, const float* __restrict__ m2,
        const float* __restrict__ v2) {
    __shared__ ShU sh;
    const int t = threadIdx.x;
    const int lane = t & 63, w = t >> 6;

    if (blockIdx.x < PBLK) {
        // ==================== FPS producer (2 batches) ====================
        FpsSh& S = sh.f;
        const int bA = blockIdx.x * 2;
        const float* XA = xyz + (size_t)bA * NPTS * 3;
        const float* XB = xyz + (size_t)(bA + 1) * NPTS * 3;

        v2f px2[2][NV], py2[2][NV], pz2[2][NV], dist2[2][NV];
#pragma unroll
        for (int j = 0; j < NV; ++j) {
            const int pA = t + FPS_T * j, pB = t + FPS_T * (j + NV);
            px2[0][j] = (v2f){XA[3 * pA + 0], XA[3 * pB + 0]};
            py2[0][j] = (v2f){XA[3 * pA + 1], XA[3 * pB + 1]};
            pz2[0][j] = (v2f){XA[3 * pA + 2], XA[3 * pB + 2]};
            px2[1][j] = (v2f){XB[3 * pA + 0], XB[3 * pB + 0]};
            py2[1][j] = (v2f){XB[3 * pA + 1], XB[3 * pB + 1]};
            pz2[1][j] = (v2f){XB[3 * pA + 2], XB[3 * pB + 2]};
            dist2[0][j] = (v2f){1e10f, 1e10f};
            dist2[1][j] = (v2f){1e10f, 1e10f};
        }
        float c0x[2] = {XA[0], XB[0]}, c0y[2] = {XA[1], XB[1]}, c0z[2] = {XA[2], XB[2]};
        float c1x[2] = {0.f, 0.f}, c1y[2] = {0.f, 0.f}, c1z[2] = {0.f, 0.f};
        int dual[2] = {0, 0};
        int E[2] = {1, 1};                   // centroid 0 pre-emitted per batch
        if (t == 0) {
            S.hx[0][0] = c0x[0]; S.hy[0][0] = c0y[0]; S.hz[0][0] = c0z[0];
            S.hx[1][0] = c0x[1]; S.hy[1][0] = c0y[1]; S.hz[1][0] = c0z[1];
        }
        int buf = 0;
        __syncthreads();

#pragma unroll 1
        while (E[0] < SCENT || E[1] < SCENT) {
            // ---------------- phase 1: update + reduce + slot ----------------
#pragma unroll
            for (int q = 0; q < 2; ++q) if (E[q] < SCENT) {
                float m2s = -1.f, s2s = -1.f;
                {
                    const v2f cxx = {c0x[q], c0x[q]}, cyy = {c0y[q], c0y[q]},
                              czz = {c0z[q], c0z[q]};
                    if (dual[q]) {
                        const v2f exx = {c1x[q], c1x[q]}, eyy = {c1y[q], c1y[q]},
                                  ezz = {c1z[q], c1z[q]};
#pragma unroll
                        for (int j = 0; j < NV; ++j) {
                            v2f dx = px2[q][j] - cxx, dy = py2[q][j] - cyy,
                                dz = pz2[q][j] - czz;
                            v2f d0 = __builtin_elementwise_fma(dx, dx,
                                     __builtin_elementwise_fma(dy, dy, dz * dz));
                            v2f ex = px2[q][j] - exx, ey = py2[q][j] - eyy,
                                ez = pz2[q][j] - ezz;
                            v2f d1 = __builtin_elementwise_fma(ex, ex,
                                     __builtin_elementwise_fma(ey, ey, ez * ez));
                            v2f d  = __builtin_elementwise_min(d0, d1);
                            v2f nd = __builtin_elementwise_min(dist2[q][j], d);
                            dist2[q][j] = nd;
                            float hi = fmaxf(nd.x, nd.y), lo = fminf(nd.x, nd.y);
                            s2s = fmaxf(fmaxf(s2s, lo), fminf(m2s, hi));
                            m2s = fmaxf(m2s, hi);
                        }
                    } else {
#pragma unroll
                        for (int j = 0; j < NV; ++j) {
                            v2f dx = px2[q][j] - cxx, dy = py2[q][j] - cyy,
                                dz = pz2[q][j] - czz;
                            v2f d  = __builtin_elementwise_fma(dx, dx,
                                     __builtin_elementwise_fma(dy, dy, dz * dz));
                            v2f nd = __builtin_elementwise_min(dist2[q][j], d);
                            dist2[q][j] = nd;
                            float hi = fmaxf(nd.x, nd.y), lo = fminf(nd.x, nd.y);
                            s2s = fmaxf(fmaxf(s2s, lo), fminf(m2s, hi));
                            m2s = fmaxf(m2s, hi);
                        }
                    }
                }
                const float m = m2s, sec = s2s;

                int mi = 0;
#pragma unroll
                for (int j = 0; j < NV; ++j) {
                    mi = (dist2[q][j].x == m) ? (t + FPS_T * j)        : mi;
                    mi = (dist2[q][j].y == m) ? (t + FPS_T * (j + NV)) : mi;
                }

                const unsigned myU = __float_as_uint(m);
                unsigned um = myU, us = __float_as_uint(sec);
                DPPTOP2(um, us, 0x111, 0xf);
                DPPTOP2(um, us, 0x112, 0xf);
                DPPTOP2(um, us, 0x114, 0xf);
                DPPTOP2(um, us, 0x118, 0xf);
                DPPTOP2(um, us, 0x142, 0xa);
                DPPTOP2(um, us, 0x143, 0xc);
                const unsigned wu  = (unsigned)__builtin_amdgcn_readlane((int)um, 63);
                const unsigned wsu = (unsigned)__builtin_amdgcn_readlane((int)us, 63);

                unsigned long long wb = __ballot(myU == wu);
                const int wl   = __ffsll(wb) - 1;
                const int widx = __builtin_amdgcn_readlane(mi, wl);
                const float thwf = __fmul_rn(__uint_as_float(wu), 0.999998f);
                unsigned long long b1m = __ballot(m >= thwf);
                unsigned long long b2m = __ballot(sec >= thwf);
                const unsigned tw = (b2m || __popcll(b1m) >= 2) ? 1u : 0u;
                if (lane == 0) {
                    *(uint4*)&S.slotQ[q][buf][w][0] =
                        make_uint4(wu, (unsigned)widx | (tw << 14), wsu, 0u);
                }
            }
            __syncthreads();                                  // the ONE barrier

            // ---------------- phase 2: combine + peel + emit ----------------
#pragma unroll
            for (int q = 0; q < 2; ++q) if (E[q] < SCENT) {
                const float* __restrict__ Xq = q ? XB : XA;
                const int gb = bA + q;

                unsigned mv[NW], mt4[NW], sv2[NW];
#pragma unroll
                for (int k = 0; k < NW; ++k) {
                    const uint4 u = *(const uint4*)&S.slotQ[q][buf][k][0];
                    mv[k] = u.x; mt4[k] = u.y; sv2[k] = u.z;
                }
                unsigned gu = mv[0];
#pragma unroll
                for (int k = 1; k < NW; ++k) gu = (mv[k] > gu) ? mv[k] : gu;
                const float gvf  = __uint_as_float(gu);
                const float gthf = __fmul_rn(gvf, 0.999998f);
                const unsigned ugth = __float_as_uint(gthf);
                int nw = 0; unsigned meta = 0; int kw = 0;
#pragma unroll
                for (int k = NW - 1; k >= 0; --k) {
                    nw  += (mv[k] >= ugth) ? 1 : 0;
                    meta = (mv[k] == gu) ? mt4[k] : meta;
                    kw   = (mv[k] == gu) ? k : kw;
                }
                const int wtie = (meta >> 14) & 1;
                int i1 = (int)(meta & 0x3fffu);
                const int fb = (nw >= 2) || wtie;

                float e0x, e0y, e0z;
                if (fb) {
                    // ---- exact f64 fallback (block-uniform, rare) ----
                    if (t == 0) S.scnt = 0;
                    __syncthreads();
#pragma unroll
                    for (int j = 0; j < NV; ++j) {
                        if (dist2[q][j].x >= gthf) {
                            int slot = atomicAdd(&S.scnt, 1);
                            if (slot < CAP) {
                                S.scandX[slot] = px2[q][j].x; S.scandY[slot] = py2[q][j].x;
                                S.scandZ[slot] = pz2[q][j].x; S.scandI[slot] = t + FPS_T * j;
                            }
                        }
                        if (dist2[q][j].y >= gthf) {
                            int slot = atomicAdd(&S.scnt, 1);
                            if (slot < CAP) {
                                S.scandX[slot] = px2[q][j].y; S.scandY[slot] = py2[q][j].y;
                                S.scandZ[slot] = pz2[q][j].y;
                                S.scandI[slot] = t + FPS_T * (j + NV);
                            }
                        }
                    }
                    __syncthreads();
                    const int mm = S.scnt;
                    if (mm <= CAP) {
                        double bd = -1.0; int bi = INT_MAX;
                        float bx = 0.f, by = 0.f, bz = 0.f;
#pragma unroll 1
                        for (int k = 0; k < mm; ++k) {
                            const float fx = S.scandX[k], fy = S.scandY[k], fz = S.scandZ[k];
                            const int   fi = S.scandI[k];
                            const double pxd = (double)fx, pyd = (double)fy,
                                         pzd = (double)fz;
                            double dd = 1e10;
                            for (int i = t; i < E[q]; i += FPS_T) {
                                double ddx = __dsub_rn(pxd, (double)S.hx[q][i]);
                                double ddy = __dsub_rn(pyd, (double)S.hy[q][i]);
                                double ddz = __dsub_rn(pzd, (double)S.hz[q][i]);
                                double d = __dadd_rn(__dadd_rn(__dmul_rn(ddx, ddx),
                                                               __dmul_rn(ddy, ddy)),
                                                     __dmul_rn(ddz, ddz));
                                dd = fmin(dd, d);
                            }
#pragma unroll
                            for (int off = 32; off >= 1; off >>= 1)
                                dd = fmin(dd, __shfl_down(dd, off));
                            if (lane == 0) S.sdd[k & 1][w] = dd;
                            __syncthreads();
                            double ddm = S.sdd[k & 1][0];
#pragma unroll
                            for (int w2i = 1; w2i < NW; ++w2i)
                                ddm = fmin(ddm, S.sdd[k & 1][w2i]);
                            if (ddm > bd || (ddm == bd && fi < bi)) {
                                bd = ddm; bi = fi; bx = fx; by = fy; bz = fz;
                            }
                        }
                        i1 = bi; e0x = bx; e0y = by; e0z = bz;
                    } else {
                        // safety net: full exact scan, re-reads coords from
                        // global (no runtime-indexed register arrays)
                        double bv = -1.0; int bi = INT_MAX;
#pragma unroll 1
                        for (int j = 0; j < 2 * NV; ++j) {
                            const int pidx = t + FPS_T * j;
                            const double pxd = (double)Xq[3 * pidx + 0];
                            const double pyd = (double)Xq[3 * pidx + 1];
                            const double pzd = (double)Xq[3 * pidx + 2];
                            double dd = 1e10;
                            for (int i = 0; i < E[q]; ++i) {
                                double ddx = __dsub_rn(pxd, (double)S.hx[q][i]);
                                double ddy = __dsub_rn(pyd, (double)S.hy[q][i]);
                                double ddz = __dsub_rn(pzd, (double)S.hz[q][i]);
                                double d = __dadd_rn(__dadd_rn(__dmul_rn(ddx, ddx),
                                                               __dmul_rn(ddy, ddy)),
                                                     __dmul_rn(ddz, ddz));
                                dd = fmin(dd, d);
                            }
                            if (dd > bv || (dd == bv && pidx < bi)) { bv = dd; bi = pidx; }
                        }
#pragma unroll
                        for (int off = 32; off >= 1; off >>= 1) {
                            double ov = __shfl_down(bv, off);
                            int    oi = __shfl_down(bi, off);
                            if (ov > bv || (ov == bv && oi < bi)) { bv = ov; bi = oi; }
                        }
                        if (lane == 0) { S.sfv[w] = bv; S.sfo[w] = bi; }
                        __syncthreads();
                        bv = S.sfv[0]; bi = S.sfo[0];
#pragma unroll
                        for (int w2i = 1; w2i < NW; ++w2i) {
                            double ov = S.sfv[w2i]; int oi = S.sfo[w2i];
                            if (ov > bv || (ov == bv && oi < bi)) { bv = ov; bi = oi; }
                        }
                        i1 = bi;
                        ULOAD3(Xq, i1, e0x, e0y, e0z);
                    }
                    __syncthreads();
                } else {
                    ULOAD3(Xq, i1, e0x, e0y, e0z);
                }

                if (t == 0) {
                    S.hx[q][E[q]] = e0x; S.hy[q][E[q]] = e0y; S.hz[q][E[q]] = e0z;
                }

                // ---- top-2 peel: emit runner-up too, when provably safe ----
                int peeled = 0;
                float e1x = 0.f, e1y = 0.f, e1z = 0.f;
                if (!fb && (E[q] + 1) < SCENT) {
                    unsigned arr[NW];
#pragma unroll
                    for (int k = 0; k < NW; ++k) arr[k] = (k == kw) ? sv2[k] : mv[k];
                    unsigned v2u = arr[0];
#pragma unroll
                    for (int k = 1; k < NW; ++k) v2u = (arr[k] > v2u) ? arr[k] : v2u;
                    int k2 = 0; unsigned meta2 = 0;
#pragma unroll
                    for (int k = NW - 1; k >= 0; --k) {
                        meta2 = (arr[k] == v2u) ? mt4[k] : meta2;
                        k2    = (arr[k] == v2u) ? k : k2;
                    }
                    const float v2vf = __uint_as_float(v2u);
                    const unsigned uthr2 = __float_as_uint(__fmul_rn(v2vf, 0.999998f));
                    int cnt = 0;
#pragma unroll
                    for (int k = 0; k < NW; ++k)
                        cnt += ((mv[k] >= uthr2) ? 1 : 0) + ((sv2[k] >= uthr2) ? 1 : 0);
                    const int i2 = (int)(meta2 & 0x3fffu);
                    ULOAD3(Xq, i2, e1x, e1y, e1z);
                    // survival: same fma-form rounding as the update sweep
                    const float ddx = e1x - e0x, ddy = e1y - e0y, ddz = e1z - e0z;
                    const float dq = fmaf(ddx, ddx, fmaf(ddy, ddy, ddz * ddz));
                    // (k2 != kw): runner-up must be another wave's max so every
                    // non-top-2 point is bounded by a VISIBLE slot sec.
                    peeled = ((k2 != kw) && (cnt == 2) &&
                              (dq >= __fmul_rn(v2vf, 1.000002f))) ? 1 : 0;
                }

                FLUSH_Q(q, gb, E[q], e0x, e0y, e0z, 0, 0.f, 0.f, 0.f);
                c0x[q] = e0x; c0y[q] = e0y; c0z[q] = e0z;

                if (peeled) {
                    const int e1i = E[q] + 1;
                    if (t == 0) {
                        S.hx[q][e1i] = e1x; S.hy[q][e1i] = e1y; S.hz[q][e1i] = e1z;
                    }
                    FLUSH_Q(q, gb, e1i, e1x, e1y, e1z, 1, e0x, e0y, e0z);
                    c1x[q] = e1x; c1y[q] = e1y; c1z[q] = e1z;
                    dual[q] = 1;
                    E[q] = e1i + 1;
                } else {
                    dual[q] = 0;
                    E[q] = E[q] + 1;
                }
            }
            buf ^= 1;
        }
    } else {
        // ============ consumers: transpose + weights + gated KNN + MLP ============
        ConsSh& K = sh.c;
        const int local = blockIdx.x - PBLK;      // 0..251
        const int batch = local / CPB;            // 0..3
        const int cl    = local % CPB;            // 0..62
        const int tx = t & 31, ty = t >> 5;       // ty 0..15

        // ---- transpose slice: (B,D,N) -> (B,N,D), 32x32 tiles ----
        for (int tid2 = local; tid2 < 2048; tid2 += NCONS) {
            const int bt = tid2 >> 9, rest = tid2 & 511;
            const int d0 = (rest >> 8) * 32, n0 = (rest & 255) * 32;
            __syncthreads();
#pragma unroll
            for (int i = 0; i < 2; ++i)
                K.tile[(ty + 16 * i) * 33 + tx] =
                    pts[(size_t)bt * DFEAT * NPTS + (size_t)(d0 + ty + 16 * i) * NPTS + n0 + tx];
            __syncthreads();
#pragma unroll
            for (int i = 0; i < 2; ++i)
                ptsT[(size_t)bt * NPTS * DFEAT + (size_t)(n0 + ty + 16 * i) * DFEAT + d0 + tx] =
                    K.tile[tx * 33 + ty + 16 * i];
        }
        if (t == 0) {
            __threadfence();                          // drain ptsT stores
            atomicAdd(tcount, 1);                     // device-scope arrival
        }

        // ---- stage folded weights in LDS ----
        for (int idx = t; idx < 64 * 68; idx += FPS_T) {
            int o = idx / 68, i = idx - o * 68;
            float v;
            if (i < 64)      v = w0[o * 67 + 3 + i];
            else if (i < 67) v = w0[o * 67 + (i - 64)];
            else             v = 0.0f;
            K.regA[idx] = v;
        }
        for (int idx = t; idx < 64 * 64; idx += FPS_T)  K.regB[idx] = w1[idx];
        for (int idx = t; idx < 128 * 64; idx += FPS_T) K.regC[idx] = w2[idx];
        if (t < 64) {
            float a0v = g0[t] / sqrtf(v0[t] + 1e-5f);
            K.prm[t]       = a0v;
            K.prm[64 + t]  = b0[t] - m0[t] * a0v;
            float a1v = g1[t] / sqrtf(v1[t] + 1e-5f);
            K.prm[128 + t] = a1v;
            K.prm[192 + t] = b1[t] - m1[t] * a1v;
        } else if (t < 192) {
            int o = t - 64;
            float a2v = g2[o] / sqrtf(v2[o] + 1e-5f);
            K.prm[256 + o] = a2v;
            K.prm[384 + o] = b2[o] - m2[o] * a2v;
        }
        // (visibility of weights across waves covered by in-round barriers)

        const float* Xb = xyz + (size_t)batch * NPTS * 3;
#pragma unroll 1
        for (int r = 0; ; ++r) {
            const int sBase = r * (CPB * NW) + cl * NW;
            if (sBase >= SCENT) break;
            const int sMax = min(sBase + NW - 1, SCENT - 1);
            if (t == 0) {
                while (__hip_atomic_load(&progress[batch], __ATOMIC_ACQUIRE,
                                         __HIP_MEMORY_SCOPE_AGENT) < sMax + 1)
                    __builtin_amdgcn_s_sleep(8);
                if (r == 0) {                         // ptsT complete before any MLP gather
                    while (__hip_atomic_load(tcount, __ATOMIC_ACQUIRE,
                                             __HIP_MEMORY_SCOPE_AGENT) < NCONS)
                        __builtin_amdgcn_s_sleep(8);
                }
            }
            __syncthreads();

            const int sQ = min(sBase + w, SCENT - 1);
            const float* q = new_xyz + ((size_t)batch * SCENT + sQ) * 3;
            const float qfx = q[0], qfy = q[1], qfz = q[2];
            const double qx = (double)qfx, qy = (double)qfy, qz = (double)qfz;
            const double q2 = __dadd_rn(__dadd_rn(__dmul_rn(qx, qx), __dmul_rn(qy, qy)),
                                        __dmul_rn(qz, qz));

            double ld   = DBL_MAX;
            int    li   = 0x7fffffff;
            double taud = DBL_MAX;
            int    taui = 0x7fffffff;

#pragma unroll 1
            for (int c = 0; c < 4; ++c) {
                __syncthreads();
#pragma unroll
                for (int r2 = 0; r2 < 4; ++r2) {
                    int pl = r2 * 512 + t;
                    int p  = c * 2048 + pl;
                    float x = Xb[3 * p + 0], y = Xb[3 * p + 1], z = Xb[3 * p + 2];
                    K.spx[pl] = x; K.spy[pl] = y; K.spz[pl] = z;
                    double dx = (double)x, dy = (double)y, dz = (double)z;
                    K.sp2[pl] = __dadd_rn(__dadd_rn(__dmul_rn(dx, dx), __dmul_rn(dy, dy)),
                                          __dmul_rn(dz, dz));
                }
                __syncthreads();
#pragma unroll 1
                for (int i = 0; i < 32; ++i) {
                    const int pl   = i * 64 + lane;
                    const int pidx = c * 2048 + pl;
                    double px = (double)K.spx[pl], py = (double)K.spy[pl],
                           pz = (double)K.spz[pl];
                    double qp = __dadd_rn(__dadd_rn(__dmul_rn(qx, px), __dmul_rn(qy, py)),
                                          __dmul_rn(qz, pz));
                    double d  = __dsub_rn(__dadd_rn(q2, K.sp2[pl]), __dmul_rn(2.0, qp));
                    bool cand = (d < taud) || (d == taud && pidx < taui);
                    unsigned long long mmask = __ballot(cand);
                    while (mmask) {
                        int sl = __ffsll((unsigned long long)mmask) - 1;
                        mmask &= mmask - 1;
                        double dv = __shfl(d, sl);
                        int    iv = __shfl(pidx, sl);
                        if (dv < taud || (dv == taud && iv < taui)) {
                            bool gt = (lane < 32) && (ld > dv || (ld == dv && li > iv));
                            unsigned long long gm = __ballot(gt);
                            double ud = __shfl_up(ld, 1);
                            int    ui = __shfl_up(li, 1);
                            if (gt) { ld = ud; li = ui; }
                            bool first = gt && ((lane == 0) || !((gm >> (lane - 1)) & 1ull));
                            if (first) { ld = dv; li = iv; }
                            taud = __shfl(ld, 31);
                            taui = __shfl(li, 31);
                        }
                    }
                }
            }

            // ---- immediate per-wave MLP (thread-per-neighbor, lanes 0..31) ----
            if (sBase + w < SCENT && lane < 32) {
                const int nidx = li;
                const float* P3 = Xb + (size_t)nidx * 3;
                const float dx = P3[0] - qfx, dy = P3[1] - qfy, dz = P3[2] - qfz;

                const float4* F = (const float4*)(ptsT + ((size_t)batch * NPTS + nidx) * 64);
                float4 xv[17];
#pragma unroll
                for (int i = 0; i < 16; ++i) xv[i] = F[i];
                xv[16] = make_float4(dx, dy, dz, 0.0f);

                float h0[64];
                const float4* W0 = (const float4*)K.regA;
#pragma unroll
                for (int o = 0; o < 64; ++o) {
                    float acc = 0.f;
#pragma unroll
                    for (int i = 0; i < 17; ++i) {
                        float4 ww = W0[o * 17 + i];
                        acc = fmaf(xv[i].x, ww.x, acc);
                        acc = fmaf(xv[i].y, ww.y, acc);
                        acc = fmaf(xv[i].z, ww.z, acc);
                        acc = fmaf(xv[i].w, ww.w, acc);
                    }
                    h0[o] = fmaxf(fmaf(acc, K.prm[o], K.prm[64 + o]), 0.f);
                }
                float h1[64];
                const float4* W1 = (const float4*)K.regB;
#pragma unroll
                for (int o = 0; o < 64; ++o) {
                    float acc = 0.f;
#pragma unroll
                    for (int i = 0; i < 16; ++i) {
                        float4 ww = W1[o * 16 + i];
                        acc = fmaf(h0[4 * i + 0], ww.x, acc);
                        acc = fmaf(h0[4 * i + 1], ww.y, acc);
                        acc = fmaf(h0[4 * i + 2], ww.z, acc);
                        acc = fmaf(h0[4 * i + 3], ww.w, acc);
                    }
                    h1[o] = fmaxf(fmaf(acc, K.prm[128 + o], K.prm[192 + o]), 0.f);
                }
                const float4* W2 = (const float4*)K.regC;
                float* outp = out_points + (size_t)batch * 128 * SCENT + sQ;
#pragma unroll 1
                for (int o = 0; o < 128; ++o) {
                    float acc = 0.f;
#pragma unroll
                    for (int i = 0; i < 16; ++i) {
                        float4 ww = W2[o * 16 + i];
                        acc = fmaf(h1[4 * i + 0], ww.x, acc);
                        acc = fmaf(h1[4 * i + 1], ww.y, acc);
                        acc = fmaf(h1[4 * i + 2], ww.z, acc);
                        acc = fmaf(h1[4 * i + 3], ww.w, acc);
                    }
                    float y = fmaxf(fmaf(acc, K.prm[256 + o], K.prm[384 + o]), 0.f);
#pragma unroll
                    for (int off = 16; off >= 1; off >>= 1)
                        y = fmaxf(y, __shfl_xor(y, off));
                    if (lane == 0) outp[(size_t)o * SCENT] = y;
                }
            }
        }
    }
}

// ---------------------------------------------------------------------------
extern "C" void kernel_launch(void* const* d_in, const int* in_sizes, int n_in,
                              void* d_out, int out_size, void* d_ws, size_t ws_size,
                              hipStream_t stream) {
    const float* xyz    = (const float*)d_in[0];
    const float* points = (const float*)d_in[1];
    const float* w0 = (const float*)d_in[2];
    const float* g0 = (const float*)d_in[3];
    const float* b0 = (const float*)d_in[4];
    const float* m0 = (const float*)d_in[5];
    const float* v0 = (const float*)d_in[6];
    const float* w1 = (const float*)d_in[7];
    const float* g1 = (const float*)d_in[8];
    const float* b1 = (const float*)d_in[9];
    const float* m1 = (const float*)d_in[10];
    const float* v1 = (const float*)d_in[11];
    const float* w2 = (const float*)d_in[12];
    const float* g2 = (const float*)d_in[13];
    const float* b2 = (const float*)d_in[14];
    const float* m2 = (const float*)d_in[15];
    const float* v2 = (const float*)d_in[16];

    float* out_xyz    = (float*)d_out;                               // (B,S,3)
    float* out_points = (float*)d_out + (size_t)BATCH * SCENT * 3;   // (B,128,S)

    char* ws = (char*)d_ws;
    int*   progress = (int*)ws;                       // 4 ints @ ws+0
    int*   tcount   = (int*)(ws + 64);                // 1 int  @ ws+64
    float* ptsT     = (float*)(ws + 32768);

    hipMemsetAsync(ws, 0, 128, stream);               // zero progress + tcount

    void* kargs[] = { (void*)&xyz, (void*)&out_xyz, (void*)&points, (void*)&ptsT,
                      (void*)&progress, (void*)&tcount, (void*)&out_points,
                      (void*)&w0, (void*)&g0, (void*)&b0, (void*)&m0, (void*)&v0,
                      (void*)&w1, (void*)&g1, (void*)&b1, (void*)&m1, (void*)&v1,
                      (void*)&w2, (void*)&g2, (void*)&b2, (void*)&m2, (void*)&v2 };
    hipLaunchCooperativeKernel((const void*)fused_kernel,
                               dim3(PBLK + NCONS), dim3(FPS_T), kargs, 0, stream);
}

// Round 3
// 2235.162 us; speedup vs baseline: 3.0931x; 3.0931x over previous
//
#include <hip/hip_runtime.h>
#include <cfloat>
#include <climits>

#define NPTS   8192
#define SCENT  2048
#define KNEIGH 32
#define BATCH  4
#define DFEAT  64
#define FPS_T  512
#define NV     8       // v2f pairs per thread (16 points)
#define NW     8       // waves per block
#define CAP    64      // fallback candidate capacity
#define NCONS  252     // consumer blocks
#define CPB    63      // consumer blocks per batch

typedef float v2f __attribute__((ext_vector_type(2)));

// DPP top-2 (max + second-max) step over uints (positive-f32 bit pattern
// preserves order). Shifted-in lanes contribute 0 (harmless for max/sec).
#define DPPTOP2(um, us, ctrl, rmask)                                                  \
    { unsigned _tm = (unsigned)__builtin_amdgcn_update_dpp(0, (int)(um), (ctrl),      \
                                                           (rmask), 0xf, false);     \
      unsigned _ts = (unsigned)__builtin_amdgcn_update_dpp(0, (int)(us), (ctrl),      \
                                                           (rmask), 0xf, false);     \
      unsigned _lo = ((um) < _tm) ? (um) : _tm;                                       \
      (us) = ((us) > _ts) ? (us) : _ts;                                               \
      (us) = ((us) > _lo) ? (us) : _lo;                                               \
      (um) = ((um) > _tm) ? (um) : _tm; }

// Flush one 64-centroid chunk + release-publish progress. The newest 1-2
// centroids are sourced from registers (e0/e1) to avoid an extra barrier
// before reading just-written LDS history.
#define FLUSH_PUB(Eidx, VX, VY, VZ, HASPREV, PX, PY, PZ)                              \
    if (((Eidx) & 63) == 63) {                                                        \
        const int base0 = (Eidx) - 63;                                                \
        if (t < 64 * 3) {                                                             \
            const int ci = base0 + t / 3;                                             \
            const int cc = t - (t / 3) * 3;                                           \
            float v;                                                                  \
            if (ci == (Eidx))                                                         \
                v = (cc == 0) ? (VX) : ((cc == 1) ? (VY) : (VZ));                     \
            else if ((HASPREV) && ci == (Eidx) - 1)                                   \
                v = (cc == 0) ? (PX) : ((cc == 1) ? (PY) : (PZ));                     \
            else                                                                      \
                v = (cc == 0) ? S.hx[ci] : ((cc == 1) ? S.hy[ci] : S.hz[ci]);         \
            __hip_atomic_store(&new_xyz[((size_t)b * SCENT + base0) * 3 + t], v,      \
                               __ATOMIC_RELAXED, __HIP_MEMORY_SCOPE_AGENT);           \
        }                                                                             \
        __syncthreads();   /* vmcnt(0) drain => stores device-visible */              \
        if (t == 0)                                                                   \
            __hip_atomic_store(&progress[b], (Eidx) + 1,                              \
                               __ATOMIC_RELEASE, __HIP_MEMORY_SCOPE_AGENT);           \
    }

struct FpsSh {                       // ~123.6 KB
    float sx[NPTS], sy[NPTS], sz[NPTS];
    float hx[SCENT], hy[SCENT], hz[SCENT];
    alignas(16) unsigned slotQ[2][NW][4];   // {m, metaM, sec, 0} per wave
    int scand[CAP];
    int scnt;
    alignas(8) double sdd[2][NW];
    double sfv[NW];
    int sfo[NW];
};
struct ConsSh {                      // ~111 KB: KNN buffers + MLP weights
    float  spx[2048], spy[2048], spz[2048];
    double sp2[2048];
    float  tile[32 * 33];
    float  regA[64 * 68];            // w0 permuted/padded
    float  regB[64 * 64];            // w1
    float  regC[128 * 64];           // w2
    float  prm[512];
};
union ShU { FpsSh f; ConsSh c; };

// ---------------------------------------------------------------------------
// Fully fused cooperative kernel.
// Blocks 0..3: FPS producer with EXTENDED TOP-2 PEELING. Per pass:
// update+DPP-top2 reduce; the runner-up w2 is emitted as the next centroid
// without another pass when provably safe: w2's next-pass value is EXACTLY
// min(v2, d_f32(w2,w1)) (same fma rounding as the sweep), and every other
// point is bounded by the visible third-best bound
// v3 = max(sec[kw], sec[k2], max_{k!=kw,k2} max[k]) (updates only shrink
// values). Peel iff min(v2,dq) > v3*(1+4e-6) and w2 is another wave's max.
// Exact ties still route through the f64 fallback (peel disabled there).
// The following pass applies both centroids in one sweep (f32 min is
// exactly associative => bit-identical dist values).
// Blocks 4..255: consumers (transpose -> gated KNN -> per-wave MLP).
// ---------------------------------------------------------------------------
__global__ __launch_bounds__(FPS_T, 1) void fused_kernel(
        const float* __restrict__ xyz, float* __restrict__ new_xyz,
        const float* __restrict__ pts, float* __restrict__ ptsT,
        int* __restrict__ progress, int* __restrict__ tcount,
        float* __restrict__ out_points,
        const float* __restrict__ w0, const float* __restrict__ g0,
        const float* __restrict__ b0, const float* __restrict__ m0,
        const float* __restrict__ v0, const float* __restrict__ w1,
        const float* __restrict__ g1, const float* __restrict__ b1,
        const float* __restrict__ m1, const float* __restrict__ v1,
        const float* __restrict__ w2, const float* __restrict__ g2,
        const float* __restrict__ b2, const float* __restrict__ m2,
        const float* __restrict__ v2) {
    __shared__ ShU sh;
    const int t = threadIdx.x;
    const int lane = t & 63, w = t >> 6;

    if (blockIdx.x < BATCH) {
        // ==================== FPS producer ====================
        FpsSh& S = sh.f;
        const int b = blockIdx.x;
        const float* X = xyz + (size_t)b * NPTS * 3;

        for (int p = t; p < NPTS; p += FPS_T) {
            S.sx[p] = X[3 * p + 0]; S.sy[p] = X[3 * p + 1]; S.sz[p] = X[3 * p + 2];
        }

        v2f px2[NV], py2[NV], pz2[NV], dist2[NV];
#pragma unroll
        for (int j = 0; j < NV; ++j) {
            int pA = t + FPS_T * j, pB = t + FPS_T * (j + NV);
            px2[j] = (v2f){X[3 * pA + 0], X[3 * pB + 0]};
            py2[j] = (v2f){X[3 * pA + 1], X[3 * pB + 1]};
            pz2[j] = (v2f){X[3 * pA + 2], X[3 * pB + 2]};
            dist2[j] = (v2f){1e10f, 1e10f};
        }
        float c0x = X[0], c0y = X[1], c0z = X[2];
        float c1x = 0.f, c1y = 0.f, c1z = 0.f;
        int dual = 0, buf = 0;
        int E = 1;                       // centroid 0 pre-emitted
        if (t == 0) { S.hx[0] = c0x; S.hy[0] = c0y; S.hz[0] = c0z; }
        __syncthreads();

#pragma unroll 1
        while (true) {
            // ---- apply pending centroid(s); track per-lane top-2 ----
            float m2s = -1.f, s2s = -1.f;
            {
                const v2f cxx = {c0x, c0x}, cyy = {c0y, c0y}, czz = {c0z, c0z};
                if (dual) {
                    const v2f exx = {c1x, c1x}, eyy = {c1y, c1y}, ezz = {c1z, c1z};
#pragma unroll
                    for (int j = 0; j < NV; ++j) {
                        v2f dx = px2[j] - cxx, dy = py2[j] - cyy, dz = pz2[j] - czz;
                        v2f d0 = __builtin_elementwise_fma(dx, dx,
                                 __builtin_elementwise_fma(dy, dy, dz * dz));
                        v2f ex = px2[j] - exx, ey = py2[j] - eyy, ez = pz2[j] - ezz;
                        v2f d1 = __builtin_elementwise_fma(ex, ex,
                                 __builtin_elementwise_fma(ey, ey, ez * ez));
                        v2f d  = __builtin_elementwise_min(d0, d1);
                        v2f nd = __builtin_elementwise_min(dist2[j], d);
                        dist2[j] = nd;
                        float hi = fmaxf(nd.x, nd.y), lo = fminf(nd.x, nd.y);
                        s2s = fmaxf(fmaxf(s2s, lo), fminf(m2s, hi));
                        m2s = fmaxf(m2s, hi);
                    }
                } else {
#pragma unroll
                    for (int j = 0; j < NV; ++j) {
                        v2f dx = px2[j] - cxx, dy = py2[j] - cyy, dz = pz2[j] - czz;
                        v2f d  = __builtin_elementwise_fma(dx, dx,
                                 __builtin_elementwise_fma(dy, dy, dz * dz));
                        v2f nd = __builtin_elementwise_min(dist2[j], d);
                        dist2[j] = nd;
                        float hi = fmaxf(nd.x, nd.y), lo = fminf(nd.x, nd.y);
                        s2s = fmaxf(fmaxf(s2s, lo), fminf(m2s, hi));
                        m2s = fmaxf(m2s, hi);
                    }
                }
            }
            const float m = m2s, sec = s2s;

            int mi = 0;
#pragma unroll
            for (int j = 0; j < NV; ++j) {
                mi = (dist2[j].x == m) ? (t + FPS_T * j)        : mi;
                mi = (dist2[j].y == m) ? (t + FPS_T * (j + NV)) : mi;
            }

            const unsigned myU = __float_as_uint(m);
            unsigned um = myU, us = __float_as_uint(sec);
            DPPTOP2(um, us, 0x111, 0xf);
            DPPTOP2(um, us, 0x112, 0xf);
            DPPTOP2(um, us, 0x114, 0xf);
            DPPTOP2(um, us, 0x118, 0xf);
            DPPTOP2(um, us, 0x142, 0xa);
            DPPTOP2(um, us, 0x143, 0xc);
            const unsigned wu  = (unsigned)__builtin_amdgcn_readlane((int)um, 63);
            const unsigned wsu = (unsigned)__builtin_amdgcn_readlane((int)us, 63);

            unsigned long long wb = __ballot(myU == wu);
            const int wl   = __ffsll(wb) - 1;
            const int widx = __builtin_amdgcn_readlane(mi, wl);
            const float thwf = __fmul_rn(__uint_as_float(wu), 0.999998f);
            unsigned long long b1m = __ballot(m >= thwf);
            unsigned long long b2m = __ballot(sec >= thwf);
            const unsigned tw = (b2m || __popcll(b1m) >= 2) ? 1u : 0u;
            if (lane == 0) {
                *(uint4*)&S.slotQ[buf][w][0] =
                    make_uint4(wu, (unsigned)widx | (tw << 14), wsu, 0u);
            }
            __syncthreads();                                  // the ONE barrier

            // ---- global combine from per-wave top-2 slots ----
            unsigned mv[NW], mt4[NW], sv2[NW];
            {
                const uint4* qp = (const uint4*)&S.slotQ[buf][0][0];
                uint4 u0 = qp[0], u1 = qp[1], u2 = qp[2], u3 = qp[3];
                uint4 u4 = qp[4], u5 = qp[5], u6 = qp[6], u7 = qp[7];
                mv[0]=u0.x; mt4[0]=u0.y; sv2[0]=u0.z;
                mv[1]=u1.x; mt4[1]=u1.y; sv2[1]=u1.z;
                mv[2]=u2.x; mt4[2]=u2.y; sv2[2]=u2.z;
                mv[3]=u3.x; mt4[3]=u3.y; sv2[3]=u3.z;
                mv[4]=u4.x; mt4[4]=u4.y; sv2[4]=u4.z;
                mv[5]=u5.x; mt4[5]=u5.y; sv2[5]=u5.z;
                mv[6]=u6.x; mt4[6]=u6.y; sv2[6]=u6.z;
                mv[7]=u7.x; mt4[7]=u7.y; sv2[7]=u7.z;
            }
            unsigned gu = mv[0];
#pragma unroll
            for (int k = 1; k < NW; ++k) gu = (mv[k] > gu) ? mv[k] : gu;
            const float gvf  = __uint_as_float(gu);
            const float gthf = __fmul_rn(gvf, 0.999998f);
            const unsigned ugth = __float_as_uint(gthf);
            int nw = 0; unsigned meta = 0; int kw = 0;
#pragma unroll
            for (int k = NW - 1; k >= 0; --k) {
                nw  += (mv[k] >= ugth) ? 1 : 0;
                meta = (mv[k] == gu) ? mt4[k] : meta;
                kw   = (mv[k] == gu) ? k : kw;
            }
            const int wtie = (meta >> 14) & 1;
            int i1 = (int)(meta & 0x3fffu);
            const int fb = (nw >= 2) || wtie;

            if (fb) {
                // ---- exact f64 fallback (block-uniform, rare) ----
                if (t == 0) S.scnt = 0;
                __syncthreads();
#pragma unroll
                for (int j = 0; j < NV; ++j) {
                    if (dist2[j].x >= gthf) {
                        int slot = atomicAdd(&S.scnt, 1);
                        if (slot < CAP) S.scand[slot] = t + FPS_T * j;
                    }
                    if (dist2[j].y >= gthf) {
                        int slot = atomicAdd(&S.scnt, 1);
                        if (slot < CAP) S.scand[slot] = t + FPS_T * (j + NV);
                    }
                }
                __syncthreads();
                const int mm = S.scnt;
                if (mm <= CAP) {
                    double bd = -1.0; int bi = INT_MAX;
#pragma unroll 1
                    for (int k = 0; k < mm; ++k) {
                        const int pos = S.scand[k];
                        const double pxd = (double)S.sx[pos], pyd = (double)S.sy[pos],
                                     pzd = (double)S.sz[pos];
                        double dd = 1e10;
                        for (int i = t; i < E; i += FPS_T) {
                            double ddx = __dsub_rn(pxd, (double)S.hx[i]);
                            double ddy = __dsub_rn(pyd, (double)S.hy[i]);
                            double ddz = __dsub_rn(pzd, (double)S.hz[i]);
                            double d = __dadd_rn(__dadd_rn(__dmul_rn(ddx, ddx), __dmul_rn(ddy, ddy)),
                                                 __dmul_rn(ddz, ddz));
                            dd = fmin(dd, d);
                        }
#pragma unroll
                        for (int off = 32; off >= 1; off >>= 1)
                            dd = fmin(dd, __shfl_down(dd, off));
                        if (lane == 0) S.sdd[k & 1][w] = dd;
                        __syncthreads();
                        double ddm = S.sdd[k & 1][0];
#pragma unroll
                        for (int w2i = 1; w2i < NW; ++w2i) ddm = fmin(ddm, S.sdd[k & 1][w2i]);
                        if (ddm > bd || (ddm == bd && pos < bi)) { bd = ddm; bi = pos; }
                    }
                    i1 = bi;
                } else {
                    // safety net: full exact scan (practically unreachable)
                    double bv = -1.0; int bi = INT_MAX;
#pragma unroll 1
                    for (int j = 0; j < 2 * NV; ++j) {
                        const int jj = j & (NV - 1);
                        const bool hiHalf = j >= NV;
                        const double pxd = (double)(hiHalf ? px2[jj].y : px2[jj].x);
                        const double pyd = (double)(hiHalf ? py2[jj].y : py2[jj].x);
                        const double pzd = (double)(hiHalf ? pz2[jj].y : pz2[jj].x);
                        double dd = 1e10;
                        for (int i = 0; i < E; ++i) {
                            double ddx = __dsub_rn(pxd, (double)S.hx[i]);
                            double ddy = __dsub_rn(pyd, (double)S.hy[i]);
                            double ddz = __dsub_rn(pzd, (double)S.hz[i]);
                            double d = __dadd_rn(__dadd_rn(__dmul_rn(ddx, ddx), __dmul_rn(ddy, ddy)),
                                                 __dmul_rn(ddz, ddz));
                            dd = fmin(dd, d);
                        }
                        int pidx = t + FPS_T * j;
                        if (dd > bv || (dd == bv && pidx < bi)) { bv = dd; bi = pidx; }
                    }
#pragma unroll
                    for (int off = 32; off >= 1; off >>= 1) {
                        double ov = __shfl_down(bv, off);
                        int    oi = __shfl_down(bi, off);
                        if (ov > bv || (ov == bv && oi < bi)) { bv = ov; bi = oi; }
                    }
                    if (lane == 0) { S.sfv[w] = bv; S.sfo[w] = bi; }
                    __syncthreads();
                    bv = S.sfv[0]; bi = S.sfo[0];
#pragma unroll
                    for (int w2i = 1; w2i < NW; ++w2i) {
                        double ov = S.sfv[w2i]; int oi = S.sfo[w2i];
                        if (ov > bv || (ov == bv && oi < bi)) { bv = ov; bi = oi; }
                    }
                    i1 = bi;
                }
                __syncthreads();
            }

            // ---- emit first centroid of this pass ----
            const float e0x = S.sx[i1], e0y = S.sy[i1], e0z = S.sz[i1];
            if (t == 0) { S.hx[E] = e0x; S.hy[E] = e0y; S.hz[E] = e0z; }
            FLUSH_PUB(E, e0x, e0y, e0z, 0, 0.f, 0.f, 0.f);
            c0x = e0x; c0y = e0y; c0z = e0z;

            // ---- extended top-2 peel: emit runner-up when provably safe ----
            int peeled = 0;
            float e1x = 0.f, e1y = 0.f, e1z = 0.f;
            if (!fb && (E + 1) < SCENT) {
                unsigned arr[NW];
#pragma unroll
                for (int k = 0; k < NW; ++k) arr[k] = (k == kw) ? sv2[k] : mv[k];
                unsigned v2u = arr[0];
#pragma unroll
                for (int k = 1; k < NW; ++k) v2u = (arr[k] > v2u) ? arr[k] : v2u;
                int k2 = 0; unsigned meta2 = 0;
#pragma unroll
                for (int k = NW - 1; k >= 0; --k) {
                    meta2 = (arr[k] == v2u) ? mt4[k] : meta2;
                    k2    = (arr[k] == v2u) ? k : k2;
                }
                // Third-best upper bound: waves kw,k2 contribute their sec
                // (their non-max points are <= sec); other waves their max.
                // Updates only shrink values, so this bounds the next pass.
                unsigned v3u = 0;
#pragma unroll
                for (int k = 0; k < NW; ++k) {
                    const unsigned cnd = (k == kw || k == k2) ? sv2[k] : mv[k];
                    v3u = (cnd > v3u) ? cnd : v3u;
                }
                const float v2vf = __uint_as_float(v2u);
                const float v3vf = __uint_as_float(v3u);
                const int i2 = (int)(meta2 & 0x3fffu);
                e1x = S.sx[i2]; e1y = S.sy[i2]; e1z = S.sz[i2];
                // w2's next-pass value = min(v2, d(w2,w1)), with d computed in
                // the SAME fma form as the update sweep (bit-exact agreement).
                const float ddx = e1x - e0x, ddy = e1y - e0y, ddz = e1z - e0z;
                const float dq = fmaf(ddx, ddx, fmaf(ddy, ddy, ddz * ddz));
                const float wnew = fminf(v2vf, dq);
                // (k2 != kw): runner-up must be another wave's max so its
                // index/coords are known and kw's rest is sec-bounded.
                // Margin 4e-6 >= 3x the mutual fma-vs-sum rounding bound;
                // exact ties at v2/v3 make the strict inequality fail => safe.
                peeled = ((k2 != kw) &&
                          (wnew > __fmul_rn(v3vf, 1.000004f))) ? 1 : 0;
            }
            if (peeled) {
                const int e1i = E + 1;
                if (t == 0) { S.hx[e1i] = e1x; S.hy[e1i] = e1y; S.hz[e1i] = e1z; }
                FLUSH_PUB(e1i, e1x, e1y, e1z, 1, e0x, e0y, e0z);
                c1x = e1x; c1y = e1y; c1z = e1z;
                dual = 1;
                E = e1i + 1;
            } else {
                dual = 0;
                E = E + 1;
            }
            if (E >= SCENT) break;
            buf ^= 1;
        }
    } else {
        // ============ consumers: transpose + weights + gated KNN + MLP ============
        ConsSh& K = sh.c;
        const int local = blockIdx.x - BATCH;     // 0..251
        const int batch = local / CPB;            // 0..3
        const int cl    = local % CPB;            // 0..62
        const int tx = t & 31, ty = t >> 5;       // ty 0..15

        // ---- transpose slice: (B,D,N) -> (B,N,D), 32x32 tiles ----
        for (int tid2 = local; tid2 < 2048; tid2 += NCONS) {
            const int bt = tid2 >> 9, rest = tid2 & 511;
            const int d0 = (rest >> 8) * 32, n0 = (rest & 255) * 32;
            __syncthreads();
#pragma unroll
            for (int i = 0; i < 2; ++i)
                K.tile[(ty + 16 * i) * 33 + tx] =
                    pts[(size_t)bt * DFEAT * NPTS + (size_t)(d0 + ty + 16 * i) * NPTS + n0 + tx];
            __syncthreads();
#pragma unroll
            for (int i = 0; i < 2; ++i)
                ptsT[(size_t)bt * NPTS * DFEAT + (size_t)(n0 + ty + 16 * i) * DFEAT + d0 + tx] =
                    K.tile[tx * 33 + ty + 16 * i];
        }
        if (t == 0) {
            __threadfence();                          // drain ptsT stores
            atomicAdd(tcount, 1);                     // device-scope arrival
        }

        // ---- stage folded weights in LDS ----
        for (int idx = t; idx < 64 * 68; idx += FPS_T) {
            int o = idx / 68, i = idx - o * 68;
            float v;
            if (i < 64)      v = w0[o * 67 + 3 + i];
            else if (i < 67) v = w0[o * 67 + (i - 64)];
            else             v = 0.0f;
            K.regA[idx] = v;
        }
        for (int idx = t; idx < 64 * 64; idx += FPS_T)  K.regB[idx] = w1[idx];
        for (int idx = t; idx < 128 * 64; idx += FPS_T) K.regC[idx] = w2[idx];
        if (t < 64) {
            float a0v = g0[t] / sqrtf(v0[t] + 1e-5f);
            K.prm[t]       = a0v;
            K.prm[64 + t]  = b0[t] - m0[t] * a0v;
            float a1v = g1[t] / sqrtf(v1[t] + 1e-5f);
            K.prm[128 + t] = a1v;
            K.prm[192 + t] = b1[t] - m1[t] * a1v;
        } else if (t < 192) {
            int o = t - 64;
            float a2v = g2[o] / sqrtf(v2[o] + 1e-5f);
            K.prm[256 + o] = a2v;
            K.prm[384 + o] = b2[o] - m2[o] * a2v;
        }
        // (visibility of weights across waves covered by in-round barriers)

        const float* Xb = xyz + (size_t)batch * NPTS * 3;
#pragma unroll 1
        for (int r = 0; ; ++r) {
            const int sBase = r * (CPB * NW) + cl * NW;
            if (sBase >= SCENT) break;
            const int sMax = min(sBase + NW - 1, SCENT - 1);
            if (t == 0) {
                while (__hip_atomic_load(&progress[batch], __ATOMIC_ACQUIRE,
                                         __HIP_MEMORY_SCOPE_AGENT) < sMax + 1)
                    __builtin_amdgcn_s_sleep(8);
                if (r == 0) {                         // ptsT complete before any MLP gather
                    while (__hip_atomic_load(tcount, __ATOMIC_ACQUIRE,
                                             __HIP_MEMORY_SCOPE_AGENT) < NCONS)
                        __builtin_amdgcn_s_sleep(8);
                }
            }
            __syncthreads();

            const int sQ = min(sBase + w, SCENT - 1);
            const float* q = new_xyz + ((size_t)batch * SCENT + sQ) * 3;
            const float qfx = q[0], qfy = q[1], qfz = q[2];
            const double qx = (double)qfx, qy = (double)qfy, qz = (double)qfz;
            const double q2 = __dadd_rn(__dadd_rn(__dmul_rn(qx, qx), __dmul_rn(qy, qy)),
                                        __dmul_rn(qz, qz));

            double ld   = DBL_MAX;
            int    li   = 0x7fffffff;
            double taud = DBL_MAX;
            int    taui = 0x7fffffff;

#pragma unroll 1
            for (int c = 0; c < 4; ++c) {
                __syncthreads();
#pragma unroll
                for (int r2 = 0; r2 < 4; ++r2) {
                    int pl = r2 * 512 + t;
                    int p  = c * 2048 + pl;
                    float x = Xb[3 * p + 0], y = Xb[3 * p + 1], z = Xb[3 * p + 2];
                    K.spx[pl] = x; K.spy[pl] = y; K.spz[pl] = z;
                    double dx = (double)x, dy = (double)y, dz = (double)z;
                    K.sp2[pl] = __dadd_rn(__dadd_rn(__dmul_rn(dx, dx), __dmul_rn(dy, dy)),
                                          __dmul_rn(dz, dz));
                }
                __syncthreads();
#pragma unroll 1
                for (int i = 0; i < 32; ++i) {
                    const int pl   = i * 64 + lane;
                    const int pidx = c * 2048 + pl;
                    double px = (double)K.spx[pl], py = (double)K.spy[pl],
                           pz = (double)K.spz[pl];
                    double qp = __dadd_rn(__dadd_rn(__dmul_rn(qx, px), __dmul_rn(qy, py)),
                                          __dmul_rn(qz, pz));
                    double d  = __dsub_rn(__dadd_rn(q2, K.sp2[pl]), __dmul_rn(2.0, qp));
                    bool cand = (d < taud) || (d == taud && pidx < taui);
                    unsigned long long mmask = __ballot(cand);
                    while (mmask) {
                        int sl = __ffsll((unsigned long long)mmask) - 1;
                        mmask &= mmask - 1;
                        double dv = __shfl(d, sl);
                        int    iv = __shfl(pidx, sl);
                        if (dv < taud || (dv == taud && iv < taui)) {
                            bool gt = (lane < 32) && (ld > dv || (ld == dv && li > iv));
                            unsigned long long gm = __ballot(gt);
                            double ud = __shfl_up(ld, 1);
                            int    ui = __shfl_up(li, 1);
                            if (gt) { ld = ud; li = ui; }
                            bool first = gt && ((lane == 0) || !((gm >> (lane - 1)) & 1ull));
                            if (first) { ld = dv; li = iv; }
                            taud = __shfl(ld, 31);
                            taui = __shfl(li, 31);
                        }
                    }
                }
            }

            // ---- immediate per-wave MLP (thread-per-neighbor, lanes 0..31) ----
            if (sBase + w < SCENT && lane < 32) {
                const int nidx = li;
                const float* P3 = Xb + (size_t)nidx * 3;
                const float dx = P3[0] - qfx, dy = P3[1] - qfy, dz = P3[2] - qfz;

                const float4* F = (const float4*)(ptsT + ((size_t)batch * NPTS + nidx) * 64);
                float4 xv[17];
#pragma unroll
                for (int i = 0; i < 16; ++i) xv[i] = F[i];
                xv[16] = make_float4(dx, dy, dz, 0.0f);

                float h0[64];
                const float4* W0 = (const float4*)K.regA;
#pragma unroll
                for (int o = 0; o < 64; ++o) {
                    float acc = 0.f;
#pragma unroll
                    for (int i = 0; i < 17; ++i) {
                        float4 ww = W0[o * 17 + i];
                        acc = fmaf(xv[i].x, ww.x, acc);
                        acc = fmaf(xv[i].y, ww.y, acc);
                        acc = fmaf(xv[i].z, ww.z, acc);
                        acc = fmaf(xv[i].w, ww.w, acc);
                    }
                    h0[o] = fmaxf(fmaf(acc, K.prm[o], K.prm[64 + o]), 0.f);
                }
                float h1[64];
                const float4* W1 = (const float4*)K.regB;
#pragma unroll
                for (int o = 0; o < 64; ++o) {
                    float acc = 0.f;
#pragma unroll
                    for (int i = 0; i < 16; ++i) {
                        float4 ww = W1[o * 16 + i];
                        acc = fmaf(h0[4 * i + 0], ww.x, acc);
                        acc = fmaf(h0[4 * i + 1], ww.y, acc);
                        acc = fmaf(h0[4 * i + 2], ww.z, acc);
                        acc = fmaf(h0[4 * i + 3], ww.w, acc);
                    }
                    h1[o] = fmaxf(fmaf(acc, K.prm[128 + o], K.prm[192 + o]), 0.f);
                }
                const float4* W2 = (const float4*)K.regC;
                float* outp = out_points + (size_t)batch * 128 * SCENT + sQ;
#pragma unroll 1
                for (int o = 0; o < 128; ++o) {
                    float acc = 0.f;
#pragma unroll
                    for (int i = 0; i < 16; ++i) {
                        float4 ww = W2[o * 16 + i];
                        acc = fmaf(h1[4 * i + 0], ww.x, acc);
                        acc = fmaf(h1[4 * i + 1], ww.y, acc);
                        acc = fmaf(h1[4 * i + 2], ww.z, acc);
                        acc = fmaf(h1[4 * i + 3], ww.w, acc);
                    }
                    float y = fmaxf(fmaf(acc, K.prm[256 + o], K.prm[384 + o]), 0.f);
#pragma unroll
                    for (int off = 16; off >= 1; off >>= 1)
                        y = fmaxf(y, __shfl_xor(y, off));
                    if (lane == 0) outp[(size_t)o * SCENT] = y;
                }
            }
        }
    }
}

// ---------------------------------------------------------------------------
extern "C" void kernel_launch(void* const* d_in, const int* in_sizes, int n_in,
                              void* d_out, int out_size, void* d_ws, size_t ws_size,
                              hipStream_t stream) {
    const float* xyz    = (const float*)d_in[0];
    const float* points = (const float*)d_in[1];
    const float* w0 = (const float*)d_in[2];
    const float* g0 = (const float*)d_in[3];
    const float* b0 = (const float*)d_in[4];
    const float* m0 = (const float*)d_in[5];
    const float* v0 = (const float*)d_in[6];
    const float* w1 = (const float*)d_in[7];
    const float* g1 = (const float*)d_in[8];
    const float* b1 = (const float*)d_in[9];
    const float* m1 = (const float*)d_in[10];
    const float* v1 = (const float*)d_in[11];
    const float* w2 = (const float*)d_in[12];
    const float* g2 = (const float*)d_in[13];
    const float* b2 = (const float*)d_in[14];
    const float* m2 = (const float*)d_in[15];
    const float* v2 = (const float*)d_in[16];

    float* out_xyz    = (float*)d_out;                               // (B,S,3)
    float* out_points = (float*)d_out + (size_t)BATCH * SCENT * 3;   // (B,128,S)

    char* ws = (char*)d_ws;
    int*   progress = (int*)ws;                       // 4 ints @ ws+0
    int*   tcount   = (int*)(ws + 64);                // 1 int  @ ws+64
    float* ptsT     = (float*)(ws + 32768);

    hipMemsetAsync(ws, 0, 128, stream);               // zero progress + tcount

    void* kargs[] = { (void*)&xyz, (void*)&out_xyz, (void*)&points, (void*)&ptsT,
                      (void*)&progress, (void*)&tcount, (void*)&out_points,
                      (void*)&w0, (void*)&g0, (void*)&b0, (void*)&m0, (void*)&v0,
                      (void*)&w1, (void*)&g1, (void*)&b1, (void*)&m1, (void*)&v1,
                      (void*)&w2, (void*)&g2, (void*)&b2, (void*)&m2, (void*)&v2 };
    hipLaunchCooperativeKernel((const void*)fused_kernel,
                               dim3(BATCH + NCONS), dim3(FPS_T), kargs, 0, stream);
}